// Round 1
// baseline (176.736 us; speedup 1.0000x reference)
//
#include <hip/hip_runtime.h>
#include <math.h>

#define NPARTS 64
#define CELL 28
#define CDIM 2048
#define BDIM 256
#define NXCD 8

// ---------------------------------------------------------------------------
// Kernel 1: distances_im (B,3,1) + val (B,) as float
// one block per image, 256 threads, C=2048 reduction vs 3 mean embeddings
// ---------------------------------------------------------------------------
__global__ __launch_bounds__(256) void k_distances(
    const float* __restrict__ emb,
    const float* __restrict__ meb,
    const float* __restrict__ mem_,
    const float* __restrict__ men,
    float* __restrict__ out)
{
    const int b = blockIdx.x;
    const int t = threadIdx.x;
    const float* e = emb + (size_t)b * CDIM;

    float sb = 0.f, sm = 0.f, sn = 0.f;
    for (int c = t; c < CDIM; c += 256) {
        float v = e[c];
        float d0 = v - meb[c];  sb += d0 * d0;
        float d1 = v - mem_[c]; sm += d1 * d1;
        float d2 = v - men[c];  sn += d2 * d2;
    }
    // intra-wave (64-lane) reduce
    for (int off = 32; off; off >>= 1) {
        sb += __shfl_down(sb, off);
        sm += __shfl_down(sm, off);
        sn += __shfl_down(sn, off);
    }
    __shared__ float red[3][4];
    const int wave = t >> 6;
    if ((t & 63) == 0) { red[0][wave] = sb; red[1][wave] = sm; red[2][wave] = sn; }
    __syncthreads();
    if (t == 0) {
        float tb = red[0][0] + red[0][1] + red[0][2] + red[0][3];
        float tm = red[1][0] + red[1][1] + red[1][2] + red[1][3];
        float tn = red[2][0] + red[2][1] + red[2][2] + red[2][3];
        float db = sqrtf(tb), dm = sqrtf(tm), dn = sqrtf(tn);
        out[b * 3 + 0] = db;
        out[b * 3 + 1] = dm;
        out[b * 3 + 2] = dn;
        // argmin, first-occurrence tie-break like jnp.argmin
        int idx = 0; float best = db;
        if (dm < best) { best = dm; idx = 1; }
        if (dn < best) { idx = 2; }
        out[3 * BDIM + b] = (float)idx;
    }
}

// ---------------------------------------------------------------------------
// Kernel 2: per-(b,p) distances to the 3 part-means.
// One wave (64 threads) per (b,p).  XCD-aware block mapping: all 64 parts of
// an image land on the same XCD (blocks dispatch round-robin g%8 -> XCD),
// so the image's feature-map lines are fetched into one L2 only.
// ---------------------------------------------------------------------------
__global__ __launch_bounds__(64) void k_dis(
    const float* __restrict__ fm,
    const float* __restrict__ mb,
    const float* __restrict__ mm,
    const float* __restrict__ mn,
    const int*   __restrict__ cx,
    const int*   __restrict__ cy,
    const int*   __restrict__ labels,
    float* __restrict__ same,
    float* __restrict__ sum3)
{
    const int g    = blockIdx.x;           // 16384 blocks
    const int xcd  = g & (NXCD - 1);
    const int slot = g >> 3;               // 0..2047 per XCD
    const int b    = xcd * (BDIM / NXCD) + (slot >> 6);   // 32 images per XCD
    const int p    = slot & (NPARTS - 1);
    const int t    = threadIdx.x;

    const int x = cx[p * BDIM + b] / CELL;   // xs[b,p] = cx[p,b] // 28
    const int y = cy[p * BDIM + b] / CELL;

    const float* f   = fm + (size_t)b * CDIM * 64 + x * 8 + y;
    const float* pmb = mb + (size_t)p * CDIM;
    const float* pmm = mm + (size_t)p * CDIM;
    const float* pmn = mn + (size_t)p * CDIM;

    float sb = 0.f, sm = 0.f, sn = 0.f;
    for (int c = t; c < CDIM; c += 64) {
        float v  = f[(size_t)c * 64];        // fm[b, c, x, y]
        float d0 = v - pmb[c]; sb += d0 * d0;
        float d1 = v - pmm[c]; sm += d1 * d1;
        float d2 = v - pmn[c]; sn += d2 * d2;
    }
    for (int off = 32; off; off >>= 1) {
        sb += __shfl_down(sb, off);
        sm += __shfl_down(sm, off);
        sn += __shfl_down(sn, off);
    }
    if (t == 0) {
        float db = sqrtf(sb), dm = sqrtf(sm), dn = sqrtf(sn);
        const int i = b * NPARTS + p;
        sum3[i] = db + dm + dn;
        const int lab = labels[b];
        same[i] = (lab == 0) ? db : ((lab == 1) ? dm : dn);
    }
}

// ---------------------------------------------------------------------------
// Kernel 3: deterministic final reduction -> loss (single block)
// ---------------------------------------------------------------------------
__global__ __launch_bounds__(256) void k_loss(
    const float* __restrict__ same,
    const float* __restrict__ sum3,
    float* __restrict__ out)
{
    const int t = threadIdx.x;
    const int N = BDIM * NPARTS;   // 16384

    double s3 = 0.0, ss = 0.0;
    for (int i = t; i < N; i += 256) { s3 += (double)sum3[i]; ss += (double)same[i]; }

    __shared__ double r1[256], r2[256];
    r1[t] = s3; r2[t] = ss;
    __syncthreads();
    for (int off = 128; off; off >>= 1) {
        if (t < off) { r1[t] += r1[t + off]; r2[t] += r2[t + off]; }
        __syncthreads();
    }
    __shared__ float dmS;
    if (t == 0) dmS = (float)((r1[0] - r2[0]) / (double)(BDIM * 2 * NPARTS));
    __syncthreads();
    const float dmean = dmS;

    double sl = 0.0;
    for (int i = t; i < N; i += 256) {
        float v = 1.0f + same[i] - dmean;
        sl += (v > 0.f) ? (double)v : 0.0;
    }
    r1[t] = sl;
    __syncthreads();
    for (int off = 128; off; off >>= 1) {
        if (t < off) r1[t] += r1[t + off];
        __syncthreads();
    }
    if (t == 0) out[3 * BDIM + BDIM] = (float)(r1[0] / (double)N);
}

extern "C" void kernel_launch(void* const* d_in, const int* in_sizes, int n_in,
                              void* d_out, int out_size, void* d_ws, size_t ws_size,
                              hipStream_t stream)
{
    const int*   labels = (const int*)  d_in[0];
    const float* emb    = (const float*)d_in[1];
    const float* fm     = (const float*)d_in[2];
    const float* mb     = (const float*)d_in[3];
    const float* mm     = (const float*)d_in[4];
    const float* mn     = (const float*)d_in[5];
    const int*   cx     = (const int*)  d_in[6];
    const int*   cy     = (const int*)  d_in[7];
    const float* meb    = (const float*)d_in[8];
    const float* mem_   = (const float*)d_in[9];
    const float* men    = (const float*)d_in[10];

    float* out  = (float*)d_out;          // [768 dist | 256 val | 1 loss]
    float* same = (float*)d_ws;           // 16384 floats
    float* sum3 = same + BDIM * NPARTS;   // 16384 floats

    k_distances<<<BDIM, 256, 0, stream>>>(emb, meb, mem_, men, out);
    k_dis<<<BDIM * NPARTS, 64, 0, stream>>>(fm, mb, mm, mn, cx, cy, labels, same, sum3);
    k_loss<<<1, 256, 0, stream>>>(same, sum3, out);
}

// Round 2
// 65.487 us; speedup vs baseline: 2.6988x; 2.6988x over previous
//
#include <hip/hip_runtime.h>
#include <math.h>

#define NPARTS 64
#define CELL 28
#define CDIM 2048
#define BDIM 256
#define SPLIT 8
#define CH_PER_BLOCK (CDIM / SPLIT)     // 256 channels per block
#define NBLK (BDIM * SPLIT)             // 2048 blocks for k_dis2

// ---- d_ws layout (float offsets) ----
#define WS_SAME   0
#define WS_SUM3   (WS_SAME + BDIM * NPARTS)           // 16384
#define WS_PART   (WS_SUM3 + BDIM * NPARTS)           // 32768, size 2048*3*64
#define WS_MBT    (WS_PART + NBLK * 3 * NPARTS)       // 425984
#define WS_MMT    (WS_MBT + CDIM * NPARTS)            // +131072
#define WS_MNT    (WS_MMT + CDIM * NPARTS)
#define WS_CELL   (WS_MNT + CDIM * NPARTS)            // int cells, 16384
// total = 835584 floats = 3.34 MB

// ---------------------------------------------------------------------------
// Prep: transpose means [p][c] -> [c/4][p][4] (so lane=p reads float4
// coalesced), and precompute cell[b][p] = (cx//28)*8 + (cy//28).
// ---------------------------------------------------------------------------
__global__ __launch_bounds__(256) void k_prep(
    const float* __restrict__ mb, const float* __restrict__ mm,
    const float* __restrict__ mn, const int* __restrict__ cx,
    const int* __restrict__ cy, float* __restrict__ ws)
{
    const int tid = blockIdx.x * 256 + threadIdx.x;
    const int NM = CDIM * NPARTS;               // 131072 = 2^17
    if (tid < 3 * NM) {
        const int kind = tid >> 17;
        const int idx  = tid & (NM - 1);
        const int p = idx >> 11;                // /2048
        const int c = idx & (CDIM - 1);
        const float* src = (kind == 0) ? mb : (kind == 1) ? mm : mn;
        float* dst = ws + ((kind == 0) ? WS_MBT : (kind == 1) ? WS_MMT : WS_MNT);
        dst[((c >> 2) << 8) + (p << 2) + (c & 3)] = src[idx];
    } else {
        const int t2 = tid - 3 * NM;
        if (t2 < BDIM * NPARTS) {
            // t2 = p*256 + b  (coalesced read of cx/cy which are [p][b])
            const int b = t2 & (BDIM - 1);
            const int p = t2 >> 8;
            const int x = cx[t2] / CELL;
            const int y = cy[t2] / CELL;
            ((int*)ws)[WS_CELL + b * NPARTS + p] = x * 8 + y;
        }
    }
}

// ---------------------------------------------------------------------------
// distances_im (B,3,1) + val (B,)
// ---------------------------------------------------------------------------
__global__ __launch_bounds__(256) void k_distances(
    const float* __restrict__ emb,
    const float* __restrict__ meb,
    const float* __restrict__ mem_,
    const float* __restrict__ men,
    float* __restrict__ out)
{
    const int b = blockIdx.x;
    const int t = threadIdx.x;
    const float* e = emb + (size_t)b * CDIM;

    float sb = 0.f, sm = 0.f, sn = 0.f;
    for (int c = t; c < CDIM; c += 256) {
        float v = e[c];
        float d0 = v - meb[c];  sb += d0 * d0;
        float d1 = v - mem_[c]; sm += d1 * d1;
        float d2 = v - men[c];  sn += d2 * d2;
    }
    for (int off = 32; off; off >>= 1) {
        sb += __shfl_down(sb, off);
        sm += __shfl_down(sm, off);
        sn += __shfl_down(sn, off);
    }
    __shared__ float red[3][4];
    const int wave = t >> 6;
    if ((t & 63) == 0) { red[0][wave] = sb; red[1][wave] = sm; red[2][wave] = sn; }
    __syncthreads();
    if (t == 0) {
        float tb = red[0][0] + red[0][1] + red[0][2] + red[0][3];
        float tm = red[1][0] + red[1][1] + red[1][2] + red[1][3];
        float tn = red[2][0] + red[2][1] + red[2][2] + red[2][3];
        float db = sqrtf(tb), dm = sqrtf(tm), dn = sqrtf(tn);
        out[b * 3 + 0] = db;
        out[b * 3 + 1] = dm;
        out[b * 3 + 2] = dn;
        int idx = 0; float best = db;
        if (dm < best) { best = dm; idx = 1; }
        if (dn < best) { idx = 2; }
        out[3 * BDIM + b] = (float)idx;
    }
}

// ---------------------------------------------------------------------------
// Main: per-(b,p) squared distances, coalesced fm reads + ds_bpermute
// redistribute. grid = B*SPLIT blocks, 256 thr (4 waves); wave w handles
// 64 channels [s*256 + w*64, +64); lane = part p.
// ---------------------------------------------------------------------------
__global__ __launch_bounds__(256) void k_dis2(
    const float* __restrict__ fm,
    float* __restrict__ ws)
{
    const int g = blockIdx.x;              // = b*8 + s
    const int b = g >> 3, s = g & 7;
    const int t = threadIdx.x;
    const int lane = t & 63, w = t >> 6;

    const int cell  = ((const int*)ws)[WS_CELL + b * NPARTS + lane];
    const int baddr = cell << 2;           // byte address for bpermute

    const int c0 = s * CH_PER_BLOCK + w * 64;     // this wave's first channel
    const float* fmb = fm + (size_t)b * (CDIM * 64) + (size_t)c0 * 64;
    const float4* mbt = (const float4*)(ws + WS_MBT) + ((c0 >> 2) << 6) + lane;
    const float4* mmt = (const float4*)(ws + WS_MMT) + ((c0 >> 2) << 6) + lane;
    const float4* mnt = (const float4*)(ws + WS_MNT) + ((c0 >> 2) << 6) + lane;

    float a0 = 0.f, a1 = 0.f, a2 = 0.f;
    #pragma unroll 4
    for (int k = 0; k < 16; ++k) {          // 4 channels per iter
        const float* r = fmb + k * 256;
        float v0 = r[lane];
        float v1 = r[64 + lane];
        float v2 = r[128 + lane];
        float v3 = r[192 + lane];
        float4 m0 = mbt[k * 64];
        float4 m1 = mmt[k * 64];
        float4 m2 = mnt[k * 64];
        float u0 = __int_as_float(__builtin_amdgcn_ds_bpermute(baddr, __float_as_int(v0)));
        float u1 = __int_as_float(__builtin_amdgcn_ds_bpermute(baddr, __float_as_int(v1)));
        float u2 = __int_as_float(__builtin_amdgcn_ds_bpermute(baddr, __float_as_int(v2)));
        float u3 = __int_as_float(__builtin_amdgcn_ds_bpermute(baddr, __float_as_int(v3)));
        float d;
        d = u0 - m0.x; a0 += d * d;  d = u1 - m0.y; a0 += d * d;
        d = u2 - m0.z; a0 += d * d;  d = u3 - m0.w; a0 += d * d;
        d = u0 - m1.x; a1 += d * d;  d = u1 - m1.y; a1 += d * d;
        d = u2 - m1.z; a1 += d * d;  d = u3 - m1.w; a1 += d * d;
        d = u0 - m2.x; a2 += d * d;  d = u1 - m2.y; a2 += d * d;
        d = u2 - m2.z; a2 += d * d;  d = u3 - m2.w; a2 += d * d;
    }

    __shared__ float red[4][3][64];
    red[w][0][lane] = a0; red[w][1][lane] = a1; red[w][2][lane] = a2;
    __syncthreads();
    if (t < 64) {
        float s0 = red[0][0][t] + red[1][0][t] + red[2][0][t] + red[3][0][t];
        float s1 = red[0][1][t] + red[1][1][t] + red[2][1][t] + red[3][1][t];
        float s2 = red[0][2][t] + red[1][2][t] + red[2][2][t] + red[3][2][t];
        float* po = ws + WS_PART + (size_t)g * 192;
        po[t] = s0; po[64 + t] = s1; po[128 + t] = s2;
    }
}

// ---------------------------------------------------------------------------
// Combine 8 channel-splits -> sqrt -> same/sum3
// ---------------------------------------------------------------------------
__global__ __launch_bounds__(256) void k_combine(
    const int* __restrict__ labels, float* __restrict__ ws)
{
    const int gid = blockIdx.x * 256 + threadIdx.x;   // 16384
    const int b = gid >> 6, p = gid & 63;
    const float* pp = ws + WS_PART + (size_t)(b * 8) * 192;
    float s0 = 0.f, s1 = 0.f, s2 = 0.f;
    #pragma unroll
    for (int s = 0; s < 8; ++s) {
        s0 += pp[s * 192 + p];
        s1 += pp[s * 192 + 64 + p];
        s2 += pp[s * 192 + 128 + p];
    }
    float db = sqrtf(s0), dm = sqrtf(s1), dn = sqrtf(s2);
    const int lab = labels[b];
    ws[WS_SAME + gid] = (lab == 0) ? db : ((lab == 1) ? dm : dn);
    ws[WS_SUM3 + gid] = db + dm + dn;
}

// ---------------------------------------------------------------------------
// Deterministic final loss (single block)
// ---------------------------------------------------------------------------
__global__ __launch_bounds__(256) void k_loss(
    const float* __restrict__ ws, float* __restrict__ out)
{
    const int t = threadIdx.x;
    const int N = BDIM * NPARTS;
    const float* same = ws + WS_SAME;
    const float* sum3 = ws + WS_SUM3;

    double s3 = 0.0, ss = 0.0;
    for (int i = t; i < N; i += 256) { s3 += (double)sum3[i]; ss += (double)same[i]; }

    __shared__ double r1[256], r2[256];
    r1[t] = s3; r2[t] = ss;
    __syncthreads();
    for (int off = 128; off; off >>= 1) {
        if (t < off) { r1[t] += r1[t + off]; r2[t] += r2[t + off]; }
        __syncthreads();
    }
    __shared__ float dmS;
    if (t == 0) dmS = (float)((r1[0] - r2[0]) / (double)(BDIM * 2 * NPARTS));
    __syncthreads();
    const float dmean = dmS;

    double sl = 0.0;
    for (int i = t; i < N; i += 256) {
        float v = 1.0f + same[i] - dmean;
        sl += (v > 0.f) ? (double)v : 0.0;
    }
    r1[t] = sl;
    __syncthreads();
    for (int off = 128; off; off >>= 1) {
        if (t < off) r1[t] += r1[t + off];
        __syncthreads();
    }
    if (t == 0) out[3 * BDIM + BDIM] = (float)(r1[0] / (double)N);
}

extern "C" void kernel_launch(void* const* d_in, const int* in_sizes, int n_in,
                              void* d_out, int out_size, void* d_ws, size_t ws_size,
                              hipStream_t stream)
{
    const int*   labels = (const int*)  d_in[0];
    const float* emb    = (const float*)d_in[1];
    const float* fm     = (const float*)d_in[2];
    const float* mb     = (const float*)d_in[3];
    const float* mm     = (const float*)d_in[4];
    const float* mn     = (const float*)d_in[5];
    const int*   cx     = (const int*)  d_in[6];
    const int*   cy     = (const int*)  d_in[7];
    const float* meb    = (const float*)d_in[8];
    const float* mem_   = (const float*)d_in[9];
    const float* men    = (const float*)d_in[10];

    float* out = (float*)d_out;
    float* ws  = (float*)d_ws;

    const int prep_work = 3 * CDIM * NPARTS + BDIM * NPARTS;   // 409600
    k_prep<<<(prep_work + 255) / 256, 256, 0, stream>>>(mb, mm, mn, cx, cy, ws);
    k_distances<<<BDIM, 256, 0, stream>>>(emb, meb, mem_, men, out);
    k_dis2<<<NBLK, 256, 0, stream>>>(fm, ws);
    k_combine<<<BDIM * NPARTS / 256, 256, 0, stream>>>(labels, ws);
    k_loss<<<1, 256, 0, stream>>>(ws, out);
}

// Round 3
// 50.491 us; speedup vs baseline: 3.5004x; 1.2970x over previous
//
#include <hip/hip_runtime.h>
#include <math.h>

#define NPARTS 64
#define CELL 28
#define CDIM 2048
#define BDIM 256
#define SPLIT 8
#define CH_PER_BLOCK (CDIM / SPLIT)     // 256 channels per block
#define NBLK (BDIM * SPLIT)             // 2048 blocks for k_dis2

// ---- d_ws layout (float offsets) ----
#define WS_SAME   0
#define WS_SUM3   (WS_SAME + BDIM * NPARTS)           // 16384
#define WS_PART   (WS_SUM3 + BDIM * NPARTS)           // 32768, size 2048*3*64
#define WS_MBT    (WS_PART + NBLK * 3 * NPARTS)       // 425984
#define WS_MMT    (WS_MBT + CDIM * NPARTS)            // +131072
#define WS_MNT    (WS_MMT + CDIM * NPARTS)
#define WS_CELL   (WS_MNT + CDIM * NPARTS)            // int cells, 16384
// total = 835584 floats = 3.34 MB

#define PREP_BLOCKS 1600   // 1600*256 = 3*CDIM*NPARTS + BDIM*NPARTS exactly

// ---------------------------------------------------------------------------
// Front kernel: blocks [0,1600) do prep (mean transpose + cell precompute);
// blocks [1600,1856) do distances_im + val for image b = g-1600.
// ---------------------------------------------------------------------------
__global__ __launch_bounds__(256) void k_front(
    const float* __restrict__ mb, const float* __restrict__ mm,
    const float* __restrict__ mn, const int* __restrict__ cx,
    const int* __restrict__ cy,
    const float* __restrict__ emb,
    const float* __restrict__ meb, const float* __restrict__ mem_,
    const float* __restrict__ men,
    float* __restrict__ ws, float* __restrict__ out)
{
    const int g = blockIdx.x;
    const int t = threadIdx.x;

    if (g < PREP_BLOCKS) {
        const int tid = g * 256 + t;
        const int NM = CDIM * NPARTS;               // 131072 = 2^17
        if (tid < 3 * NM) {
            const int kind = tid >> 17;
            const int idx  = tid & (NM - 1);
            const int p = idx >> 11;                // /2048
            const int c = idx & (CDIM - 1);
            const float* src = (kind == 0) ? mb : (kind == 1) ? mm : mn;
            float* dst = ws + ((kind == 0) ? WS_MBT : (kind == 1) ? WS_MMT : WS_MNT);
            dst[((c >> 2) << 8) + (p << 2) + (c & 3)] = src[idx];
        } else {
            const int t2 = tid - 3 * NM;            // < BDIM*NPARTS
            const int b = t2 & (BDIM - 1);
            const int p = t2 >> 8;
            const int x = cx[t2] / CELL;
            const int y = cy[t2] / CELL;
            ((int*)ws)[WS_CELL + b * NPARTS + p] = x * 8 + y;
        }
        return;
    }

    // ---- distances part ----
    const int b = g - PREP_BLOCKS;
    const float* e = emb + (size_t)b * CDIM;

    float sb = 0.f, sm = 0.f, sn = 0.f;
    for (int c = t; c < CDIM; c += 256) {
        float v = e[c];
        float d0 = v - meb[c];  sb += d0 * d0;
        float d1 = v - mem_[c]; sm += d1 * d1;
        float d2 = v - men[c];  sn += d2 * d2;
    }
    for (int off = 32; off; off >>= 1) {
        sb += __shfl_down(sb, off);
        sm += __shfl_down(sm, off);
        sn += __shfl_down(sn, off);
    }
    __shared__ float red[3][4];
    const int wave = t >> 6;
    if ((t & 63) == 0) { red[0][wave] = sb; red[1][wave] = sm; red[2][wave] = sn; }
    __syncthreads();
    if (t == 0) {
        float tb = red[0][0] + red[0][1] + red[0][2] + red[0][3];
        float tm = red[1][0] + red[1][1] + red[1][2] + red[1][3];
        float tn = red[2][0] + red[2][1] + red[2][2] + red[2][3];
        float db = sqrtf(tb), dm = sqrtf(tm), dn = sqrtf(tn);
        out[b * 3 + 0] = db;
        out[b * 3 + 1] = dm;
        out[b * 3 + 2] = dn;
        int idx = 0; float best = db;
        if (dm < best) { best = dm; idx = 1; }
        if (dn < best) { idx = 2; }
        out[3 * BDIM + b] = (float)idx;
    }
}

// ---------------------------------------------------------------------------
// Main: per-(b,p) squared distances, coalesced fm reads + ds_bpermute
// redistribute. grid = B*SPLIT blocks, 256 thr (4 waves); wave w handles
// 64 channels [s*256 + w*64, +64); lane = part p.
// ---------------------------------------------------------------------------
__global__ __launch_bounds__(256) void k_dis2(
    const float* __restrict__ fm,
    float* __restrict__ ws)
{
    const int g = blockIdx.x;              // = b*8 + s
    const int b = g >> 3, s = g & 7;
    const int t = threadIdx.x;
    const int lane = t & 63, w = t >> 6;

    const int cell  = ((const int*)ws)[WS_CELL + b * NPARTS + lane];
    const int baddr = cell << 2;           // byte address for bpermute

    const int c0 = s * CH_PER_BLOCK + w * 64;     // this wave's first channel
    const float* fmb = fm + (size_t)b * (CDIM * 64) + (size_t)c0 * 64;
    const float4* mbt = (const float4*)(ws + WS_MBT) + ((c0 >> 2) << 6) + lane;
    const float4* mmt = (const float4*)(ws + WS_MMT) + ((c0 >> 2) << 6) + lane;
    const float4* mnt = (const float4*)(ws + WS_MNT) + ((c0 >> 2) << 6) + lane;

    float a0 = 0.f, a1 = 0.f, a2 = 0.f;
    #pragma unroll 4
    for (int k = 0; k < 16; ++k) {          // 4 channels per iter
        const float* r = fmb + k * 256;
        float v0 = r[lane];
        float v1 = r[64 + lane];
        float v2 = r[128 + lane];
        float v3 = r[192 + lane];
        float4 m0 = mbt[k * 64];
        float4 m1 = mmt[k * 64];
        float4 m2 = mnt[k * 64];
        float u0 = __int_as_float(__builtin_amdgcn_ds_bpermute(baddr, __float_as_int(v0)));
        float u1 = __int_as_float(__builtin_amdgcn_ds_bpermute(baddr, __float_as_int(v1)));
        float u2 = __int_as_float(__builtin_amdgcn_ds_bpermute(baddr, __float_as_int(v2)));
        float u3 = __int_as_float(__builtin_amdgcn_ds_bpermute(baddr, __float_as_int(v3)));
        float d;
        d = u0 - m0.x; a0 += d * d;  d = u1 - m0.y; a0 += d * d;
        d = u2 - m0.z; a0 += d * d;  d = u3 - m0.w; a0 += d * d;
        d = u0 - m1.x; a1 += d * d;  d = u1 - m1.y; a1 += d * d;
        d = u2 - m1.z; a1 += d * d;  d = u3 - m1.w; a1 += d * d;
        d = u0 - m2.x; a2 += d * d;  d = u1 - m2.y; a2 += d * d;
        d = u2 - m2.z; a2 += d * d;  d = u3 - m2.w; a2 += d * d;
    }

    __shared__ float red[4][3][64];
    red[w][0][lane] = a0; red[w][1][lane] = a1; red[w][2][lane] = a2;
    __syncthreads();
    if (t < 64) {
        float s0 = red[0][0][t] + red[1][0][t] + red[2][0][t] + red[3][0][t];
        float s1 = red[0][1][t] + red[1][1][t] + red[2][1][t] + red[3][1][t];
        float s2 = red[0][2][t] + red[1][2][t] + red[2][2][t] + red[3][2][t];
        float* po = ws + WS_PART + (size_t)g * 192;
        po[t] = s0; po[64 + t] = s1; po[128 + t] = s2;
    }
}

// ---------------------------------------------------------------------------
// Combine 8 channel-splits -> sqrt -> same/sum3
// ---------------------------------------------------------------------------
__global__ __launch_bounds__(256) void k_combine(
    const int* __restrict__ labels, float* __restrict__ ws)
{
    const int gid = blockIdx.x * 256 + threadIdx.x;   // 16384
    const int b = gid >> 6, p = gid & 63;
    const float* pp = ws + WS_PART + (size_t)(b * 8) * 192;
    float s0 = 0.f, s1 = 0.f, s2 = 0.f;
    #pragma unroll
    for (int s = 0; s < 8; ++s) {
        s0 += pp[s * 192 + p];
        s1 += pp[s * 192 + 64 + p];
        s2 += pp[s * 192 + 128 + p];
    }
    float db = sqrtf(s0), dm = sqrtf(s1), dn = sqrtf(s2);
    const int lab = labels[b];
    ws[WS_SAME + gid] = (lab == 0) ? db : ((lab == 1) ? dm : dn);
    ws[WS_SUM3 + gid] = db + dm + dn;
}

// ---------------------------------------------------------------------------
// Deterministic final loss (single block, 512 threads)
// ---------------------------------------------------------------------------
__global__ __launch_bounds__(512) void k_loss(
    const float* __restrict__ ws, float* __restrict__ out)
{
    const int t = threadIdx.x;
    const int N = BDIM * NPARTS;
    const float* same = ws + WS_SAME;
    const float* sum3 = ws + WS_SUM3;

    double s3 = 0.0, ss = 0.0;
    for (int i = t; i < N; i += 512) { s3 += (double)sum3[i]; ss += (double)same[i]; }

    __shared__ double r1[512], r2[512];
    r1[t] = s3; r2[t] = ss;
    __syncthreads();
    for (int off = 256; off; off >>= 1) {
        if (t < off) { r1[t] += r1[t + off]; r2[t] += r2[t + off]; }
        __syncthreads();
    }
    __shared__ float dmS;
    if (t == 0) dmS = (float)((r1[0] - r2[0]) / (double)(BDIM * 2 * NPARTS));
    __syncthreads();
    const float dmean = dmS;

    double sl = 0.0;
    for (int i = t; i < N; i += 512) {
        float v = 1.0f + same[i] - dmean;
        sl += (v > 0.f) ? (double)v : 0.0;
    }
    r1[t] = sl;
    __syncthreads();
    for (int off = 256; off; off >>= 1) {
        if (t < off) r1[t] += r1[t + off];
        __syncthreads();
    }
    if (t == 0) out[3 * BDIM + BDIM] = (float)(r1[0] / (double)N);
}

extern "C" void kernel_launch(void* const* d_in, const int* in_sizes, int n_in,
                              void* d_out, int out_size, void* d_ws, size_t ws_size,
                              hipStream_t stream)
{
    const int*   labels = (const int*)  d_in[0];
    const float* emb    = (const float*)d_in[1];
    const float* fm     = (const float*)d_in[2];
    const float* mb     = (const float*)d_in[3];
    const float* mm     = (const float*)d_in[4];
    const float* mn     = (const float*)d_in[5];
    const int*   cx     = (const int*)  d_in[6];
    const int*   cy     = (const int*)  d_in[7];
    const float* meb    = (const float*)d_in[8];
    const float* mem_   = (const float*)d_in[9];
    const float* men    = (const float*)d_in[10];

    float* out = (float*)d_out;
    float* ws  = (float*)d_ws;

    k_front<<<PREP_BLOCKS + BDIM, 256, 0, stream>>>(mb, mm, mn, cx, cy,
                                                    emb, meb, mem_, men, ws, out);
    k_dis2<<<NBLK, 256, 0, stream>>>(fm, ws);
    k_combine<<<BDIM * NPARTS / 256, 256, 0, stream>>>(labels, ws);
    k_loss<<<1, 512, 0, stream>>>(ws, out);
}